// Round 7
// baseline (179.843 us; speedup 1.0000x reference)
//
#include <hip/hip_runtime.h>
#include <hip/hip_bf16.h>
#include <stdint.h>

// MoE: B=8, N=8192, D=128, C=128, E=8, K=2. Tokens T = 65536.
#define Dd 128
#define Cc 128
#define Ee 8
#define TM 64
#define NTOK 65536

using f32x4  = __attribute__((ext_vector_type(4))) float;
using short8 = __attribute__((ext_vector_type(8))) short;
typedef unsigned short u16;

__device__ inline u16 f2bf(float f) {
    union { __hip_bfloat16 h; u16 u; } cv;
    cv.h = __float2bfloat16(f);
    return cv.u;
}

// Pre-pass: expert_w [E][D][C] fp32 -> wt [E][C][D] bf16, with the 16B-chunk
// XOR swizzle PRE-APPLIED in global memory so that a linear global_load_lds
// copy produces the swizzled LDS layout (rule: linear dest + inv-swz source).
// chunk (row c, k-chunk d>>3) stored at slot (d>>3)^(c&7) within row c.
__global__ __launch_bounds__(256) void transpose_w(const float* __restrict__ w,
                                                   u16* __restrict__ wt) {
    int idx = blockIdx.x * 256 + threadIdx.x;   // 131072 = E*D*C
    int d = idx & 127;
    int c = (idx >> 7) & 127;
    int e = idx >> 14;
    int slot = (d >> 3) ^ (c & 7);
    wt[(e << 14) + (c << 7) + (slot << 3) + (d & 7)] =
        f2bf(w[(e << 14) + (d << 7) + c]);
}

// Issue 32KB expert tile -> LDS via async global_load_lds (16B/lane).
__device__ __forceinline__ void stage_expert(const u16* __restrict__ wt, int e,
                                             u16* dst, int tid) {
    const u16* src = wt + ((size_t)e << 14);
    int wave = tid >> 6;
    #pragma unroll
    for (int j = 0; j < 8; ++j) {
        int chunk = (j << 8) + tid;                  // 0..2047
        const u16* g = src + (chunk << 3);           // per-lane global addr
        u16* l = dst + ((((j << 8) + (wave << 6))) << 3);  // wave-uniform base
        __builtin_amdgcn_global_load_lds(
            (const __attribute__((address_space(1))) unsigned int*)g,
            (__attribute__((address_space(3))) unsigned int*)l,
            16, 0, 0);
    }
}

__global__ __launch_bounds__(256, 2) void moe_main(
    const float* __restrict__ x,    // [T][D]
    const float* __restrict__ rw,   // [D][E]
    const float* __restrict__ rb,   // [E]
    const float* __restrict__ eb,   // [E][C]
    const u16*   __restrict__ wt,   // [E] swizzled W^T bf16
    float*       __restrict__ out)  // [T][C]
{
    __shared__ __align__(16) u16 Ws[2][Cc * Dd];   // 2 x 32 KB double buffer
    __shared__ float glg[TM * Ee];                 // logits, then gates

    const int tid  = threadIdx.x;
    const int t0   = blockIdx.x * TM;
    const int lane = tid & 63;
    const int wave = tid >> 6;
    const int m0   = (wave >> 1) * 32;   // wave -> 32x64 output sub-tile
    const int n0   = (wave & 1) * 64;
    const int ln15 = lane & 15;
    const int kg   = lane >> 4;

    // ---- issue stage of expert 0 (flies under router + frag loads) ----
    stage_expert(wt, 0, Ws[0], tid);

    // ---- router logits: thread -> one token row, two experts; fp64 acc ----
    {
        int p  = tid * 2;                 // even: e0, e0+1 same token
        int tk = p >> 3, e0 = p & 7;
        const float4* xr = (const float4*)(x + (size_t)(t0 + tk) * Dd);
        double a0 = (double)rb[e0], a1 = (double)rb[e0 + 1];
        #pragma unroll 8
        for (int q = 0; q < 32; ++q) {
            float4 v = xr[q];
            #pragma unroll
            for (int u = 0; u < 4; ++u) {
                double xv = (double)((const float*)&v)[u];
                a0 += xv * (double)rw[(q * 4 + u) * Ee + e0];
                a1 += xv * (double)rw[(q * 4 + u) * Ee + e0 + 1];
            }
        }
        glg[p] = (float)a0;
        glg[p + 1] = (float)a1;
    }

    // ---- A-fragments direct from global x (L1/L2-hot), once per block ----
    short8 af[2][4];
    #pragma unroll
    for (int mi = 0; mi < 2; ++mi) {
        int r = t0 + m0 + mi * 16 + ln15;
        #pragma unroll
        for (int ks = 0; ks < 4; ++ks) {
            const float4* s = (const float4*)(x + (size_t)r * Dd + (ks * 4 + kg) * 8);
            float4 a = s[0], b = s[1];
            short8 v;
            v[0] = (short)f2bf(a.x); v[1] = (short)f2bf(a.y);
            v[2] = (short)f2bf(a.z); v[3] = (short)f2bf(a.w);
            v[4] = (short)f2bf(b.x); v[5] = (short)f2bf(b.y);
            v[6] = (short)f2bf(b.z); v[7] = (short)f2bf(b.w);
            af[mi][ks] = v;
        }
    }

    __syncthreads();   // drains vmcnt: Ws[0] ready; logits visible

    f32x4 oacc[2][4] = {};

    for (int e = 0; e < Ee; ++e) {
        const u16* wsc = Ws[e & 1];
        if (e < Ee - 1) stage_expert(wt, e + 1, Ws[(e + 1) & 1], tid);

        f32x4 acc[2][4] = {};
        #pragma unroll
        for (int ks = 0; ks < 4; ++ks) {
            short8 bfr[4];
            int cc = ks * 4 + kg;
            #pragma unroll
            for (int ni = 0; ni < 4; ++ni) {
                int r = n0 + ni * 16 + ln15;
                bfr[ni] = *(const short8*)&wsc[r * Dd + ((cc ^ (r & 7)) << 3)];
            }
            #pragma unroll
            for (int mi = 0; mi < 2; ++mi)
                #pragma unroll
                for (int ni = 0; ni < 4; ++ni)
                    acc[mi][ni] = __builtin_amdgcn_mfma_f32_16x16x32_bf16(
                        af[mi][ks], bfr[ni], acc[mi][ni], 0, 0, 0);
        }

        if (e == 0) {
            // gates (tid<64): logits -> top2 -> renormalized gates in glg
            if (tid < TM) {
                float l[Ee];
                #pragma unroll
                for (int k = 0; k < Ee; ++k) l[k] = glg[tid * Ee + k];
                int e0 = 0;
                #pragma unroll
                for (int k = 1; k < Ee; ++k) if (l[k] > l[e0]) e0 = k;
                int e1 = (e0 == 0) ? 1 : 0;
                #pragma unroll
                for (int k = 0; k < Ee; ++k)
                    if (k != e0 && l[k] > l[e1]) e1 = k;
                float g1 = __expf(l[e1] - l[e0]);
                float s  = 1.0f + g1;
                float g0 = 1.0f / s; g1 = g1 / s;
                #pragma unroll
                for (int k = 0; k < Ee; ++k) glg[tid * Ee + k] = 0.0f;
                glg[tid * Ee + e0] = g0;
                glg[tid * Ee + e1] = g1;
            }
            __syncthreads();   // Ws[1] ready + gates visible
            float bb[4];
            #pragma unroll
            for (int ni = 0; ni < 4; ++ni) bb[ni] = eb[e * Cc + n0 + ni * 16 + ln15];
            #pragma unroll
            for (int mi = 0; mi < 2; ++mi)
                #pragma unroll
                for (int r = 0; r < 4; ++r) {
                    float g = glg[(m0 + mi * 16 + kg * 4 + r) * Ee + e];
                    #pragma unroll
                    for (int ni = 0; ni < 4; ++ni)
                        oacc[mi][ni][r] += g * (acc[mi][ni][r] + bb[ni]);
                }
        } else {
            // epilogue BEFORE barrier (gates stable; extends stage cover)
            float bb[4];
            #pragma unroll
            for (int ni = 0; ni < 4; ++ni) bb[ni] = eb[e * Cc + n0 + ni * 16 + ln15];
            #pragma unroll
            for (int mi = 0; mi < 2; ++mi)
                #pragma unroll
                for (int r = 0; r < 4; ++r) {
                    float g = glg[(m0 + mi * 16 + kg * 4 + r) * Ee + e];
                    #pragma unroll
                    for (int ni = 0; ni < 4; ++ni)
                        oacc[mi][ni][r] += g * (acc[mi][ni][r] + bb[ni]);
                }
            __syncthreads();   // drains vmcnt: Ws[(e+1)&1] ready
        }
    }

    // ---- write out ----
    #pragma unroll
    for (int mi = 0; mi < 2; ++mi)
        #pragma unroll
        for (int r = 0; r < 4; ++r) {
            size_t row = (size_t)(t0 + m0 + mi * 16 + kg * 4 + r);
            #pragma unroll
            for (int ni = 0; ni < 4; ++ni)
                out[row * Cc + n0 + ni * 16 + ln15] = oacc[mi][ni][r];
        }
}

extern "C" void kernel_launch(void* const* d_in, const int* in_sizes, int n_in,
                              void* d_out, int out_size, void* d_ws, size_t ws_size,
                              hipStream_t stream) {
    const float* x  = (const float*)d_in[0];
    const float* rw = (const float*)d_in[1];
    const float* rb = (const float*)d_in[2];
    const float* ew = (const float*)d_in[3];
    const float* eb = (const float*)d_in[4];
    float* out = (float*)d_out;
    u16* wt = (u16*)d_ws;                       // 256 KB swizzled bf16 W^T

    transpose_w<<<dim3(512), dim3(256), 0, stream>>>(ew, wt);
    moe_main<<<dim3(NTOK / TM), dim3(256), 0, stream>>>(x, rw, rb, eb, wt, out);
}

// Round 10
// 136.842 us; speedup vs baseline: 1.3142x; 1.3142x over previous
//
#include <hip/hip_runtime.h>
#include <hip/hip_bf16.h>
#include <stdint.h>

// MoE: B=8, N=8192, D=128, C=128, E=8, K=2. Tokens T = 65536.
#define Dd 128
#define Cc 128
#define Ee 8
#define TM 64
#define NTOK 65536

using f32x4  = __attribute__((ext_vector_type(4))) float;
using short8 = __attribute__((ext_vector_type(8))) short;
typedef unsigned short u16;

__device__ inline u16 f2bf(float f) {
    union { __hip_bfloat16 h; u16 u; } cv;
    cv.h = __float2bfloat16(f);
    return cv.u;
}

// Pre-pass: expert_w [E][D][C] fp32 -> wt = swizzled W^T bf16.
// Output chunk (row c, k-chunk cc) lives at slot cc^(c&7) within row c, so a
// LINEAR copy into LDS yields the swizzled tile. One thread per 16B chunk:
// gather 8 strided floats (L2-resident, w=512KB), write coalesced 16B.
__global__ __launch_bounds__(256) void transpose_w(const float* __restrict__ w,
                                                   u16* __restrict__ wt) {
    int id = blockIdx.x * 256 + threadIdx.x;   // 16384 chunks = E*128*16
    int cc = id & 15;
    int c  = (id >> 4) & 127;
    int e  = id >> 11;
    const float* src = w + (e << 14) + (cc << 3) * Dd + c;  // w[e][cc*8+k][c]
    u16 tmp[8];
    #pragma unroll
    for (int k = 0; k < 8; ++k) tmp[k] = f2bf(src[k * Dd]);
    int slot = cc ^ (c & 7);
    *(int4*)&wt[(e << 14) + (c << 7) + (slot << 3)] = *(const int4*)tmp;
}

__global__ __launch_bounds__(256, 2) void moe_main(
    const float* __restrict__ x,    // [T][D]
    const float* __restrict__ rw,   // [D][E]
    const float* __restrict__ rb,   // [E]
    const float* __restrict__ eb,   // [E][C]
    const u16*   __restrict__ wt,   // [E] swizzled W^T bf16
    float*       __restrict__ out)  // [T][C]
{
    __shared__ __align__(16) u16 Ws[2][Cc * Dd];   // 2 x 32 KB double buffer
    __shared__ float glg[TM * Ee];                 // logits, then gates

    const int tid  = threadIdx.x;
    const int t0   = blockIdx.x * TM;
    const int lane = tid & 63;
    const int wave = tid >> 6;
    const int m0   = (wave >> 1) * 32;   // wave -> 32x64 output sub-tile
    const int n0   = (wave & 1) * 64;
    const int ln15 = lane & 15;
    const int kg   = lane >> 4;

    // ---- issue W[0] loads first (deepest latency) ----
    int4 rstg[8];
    {
        const int4* src = (const int4*)wt;         // expert 0
        #pragma unroll
        for (int j = 0; j < 8; ++j) rstg[j] = src[j * 256 + tid];
    }

    // ---- router logits from GLOBAL x (no LDS conflicts); fp64 acc ----
    {
        int p  = tid * 2;                 // token tid/4, experts p&7, +1
        int tk = p >> 3, e0 = p & 7;
        const float4* xr = (const float4*)(x + (size_t)(t0 + tk) * Dd);
        double a0 = (double)rb[e0], a1 = (double)rb[e0 + 1];
        #pragma unroll 8
        for (int q = 0; q < 32; ++q) {
            float4 v = xr[q];
            #pragma unroll
            for (int u = 0; u < 4; ++u) {
                double xv = (double)((const float*)&v)[u];
                a0 += xv * (double)rw[(q * 4 + u) * Ee + e0];
                a1 += xv * (double)rw[(q * 4 + u) * Ee + e0 + 1];
            }
        }
        glg[p] = (float)a0;
        glg[p + 1] = (float)a1;
    }

    // ---- A-fragments direct from global x (L1/L2-hot), expert-invariant ----
    short8 af[2][4];
    #pragma unroll
    for (int mi = 0; mi < 2; ++mi) {
        int r = t0 + m0 + mi * 16 + ln15;
        #pragma unroll
        for (int ks = 0; ks < 4; ++ks) {
            const float4* s = (const float4*)(x + (size_t)r * Dd + (ks * 4 + kg) * 8);
            float4 a = s[0], b = s[1];
            short8 v;
            v[0] = (short)f2bf(a.x); v[1] = (short)f2bf(a.y);
            v[2] = (short)f2bf(a.z); v[3] = (short)f2bf(a.w);
            v[4] = (short)f2bf(b.x); v[5] = (short)f2bf(b.y);
            v[6] = (short)f2bf(b.z); v[7] = (short)f2bf(b.w);
            af[mi][ks] = v;
        }
    }

    // ---- write staged W[0] to LDS (vmcnt waited by compiler) ----
    {
        int4* dst = (int4*)Ws[0];
        #pragma unroll
        for (int j = 0; j < 8; ++j) dst[j * 256 + tid] = rstg[j];
    }
    __syncthreads();   // Ws[0] + logits visible

    // ---- gates (tid<64); read at epilogue e=0, after iter-0 barrier ----
    if (tid < TM) {
        float l[Ee];
        #pragma unroll
        for (int k = 0; k < Ee; ++k) l[k] = glg[tid * Ee + k];
        int e0 = 0;
        #pragma unroll
        for (int k = 1; k < Ee; ++k) if (l[k] > l[e0]) e0 = k;
        int e1 = (e0 == 0) ? 1 : 0;
        #pragma unroll
        for (int k = 0; k < Ee; ++k)
            if (k != e0 && l[k] > l[e1]) e1 = k;
        float g1 = __expf(l[e1] - l[e0]);
        float s  = 1.0f + g1;
        float g0 = 1.0f / s; g1 = g1 / s;
        #pragma unroll
        for (int k = 0; k < Ee; ++k) glg[tid * Ee + k] = 0.0f;
        glg[tid * Ee + e0] = g0;
        glg[tid * Ee + e1] = g1;
    }

    f32x4 oacc[2][4] = {};

    for (int e = 0; e < Ee; ++e) {
        // issue next expert's loads (fly under this expert's MFMA)
        if (e < Ee - 1) {
            const int4* src = (const int4*)(wt + ((size_t)(e + 1) << 14));
            #pragma unroll
            for (int j = 0; j < 8; ++j) rstg[j] = src[j * 256 + tid];
        }

        const u16* wsc = Ws[e & 1];
        f32x4 acc[2][4] = {};
        #pragma unroll
        for (int ks = 0; ks < 4; ++ks) {
            short8 bfr[4];
            int cc = ks * 4 + kg;
            #pragma unroll
            for (int ni = 0; ni < 4; ++ni) {
                int r = n0 + ni * 16 + ln15;
                bfr[ni] = *(const short8*)&wsc[r * Dd + ((cc ^ (r & 7)) << 3)];
            }
            #pragma unroll
            for (int mi = 0; mi < 2; ++mi)
                #pragma unroll
                for (int ni = 0; ni < 4; ++ni)
                    acc[mi][ni] = __builtin_amdgcn_mfma_f32_16x16x32_bf16(
                        af[mi][ks], bfr[ni], acc[mi][ni], 0, 0, 0);
        }

        // write next buffer (other half; prev reads fenced by last barrier)
        if (e < Ee - 1) {
            int4* dst = (int4*)Ws[(e + 1) & 1];
            #pragma unroll
            for (int j = 0; j < 8; ++j) dst[j * 256 + tid] = rstg[j];
        }
        __syncthreads();   // next Ws ready; (e==0) gates now visible

        // epilogue after barrier: overlaps next iter's loads on other waves
        float bb[4];
        #pragma unroll
        for (int ni = 0; ni < 4; ++ni) bb[ni] = eb[e * Cc + n0 + ni * 16 + ln15];
        #pragma unroll
        for (int mi = 0; mi < 2; ++mi)
            #pragma unroll
            for (int r = 0; r < 4; ++r) {
                float g = glg[(m0 + mi * 16 + kg * 4 + r) * Ee + e];
                #pragma unroll
                for (int ni = 0; ni < 4; ++ni)
                    oacc[mi][ni][r] += g * (acc[mi][ni][r] + bb[ni]);
            }
    }

    // ---- write out ----
    #pragma unroll
    for (int mi = 0; mi < 2; ++mi)
        #pragma unroll
        for (int r = 0; r < 4; ++r) {
            size_t row = (size_t)(t0 + m0 + mi * 16 + kg * 4 + r);
            #pragma unroll
            for (int ni = 0; ni < 4; ++ni)
                out[row * Cc + n0 + ni * 16 + ln15] = oacc[mi][ni][r];
        }
}

extern "C" void kernel_launch(void* const* d_in, const int* in_sizes, int n_in,
                              void* d_out, int out_size, void* d_ws, size_t ws_size,
                              hipStream_t stream) {
    const float* x  = (const float*)d_in[0];
    const float* rw = (const float*)d_in[1];
    const float* rb = (const float*)d_in[2];
    const float* ew = (const float*)d_in[3];
    const float* eb = (const float*)d_in[4];
    float* out = (float*)d_out;
    u16* wt = (u16*)d_ws;                       // 256 KB swizzled bf16 W^T

    transpose_w<<<dim3(64), dim3(256), 0, stream>>>(ew, wt);
    moe_main<<<dim3(NTOK / TM), dim3(256), 0, stream>>>(x, rw, rb, eb, wt, out);
}